// Round 8
// baseline (88.744 us; speedup 1.0000x reference)
//
#include <hip/hip_runtime.h>
#include <math.h>

#define BATCH 8
#define H 256
#define W 256
#define NPIX (BATCH * H * W)
#define CT 2                      // columns per block -> 1024 blocks = 4/CU
#define NBLK (BATCH * (W / CT))   // 1024
#define NROWS (BATCH * H)

__device__ __forceinline__ float bce_logits(float p, float t) {
    return fmaxf(p, 0.0f) - p * t + log1pf(expf(-fabsf(p)));
}

// K1: zero-pixel bitmasks per row (64 KB, stays L2-hot for K2).
// Also zero-inits the ticket counter used by K2's last-block reduction.
__global__ void __launch_bounds__(256) make_masks(const float* __restrict__ target,
                                                  unsigned long long* __restrict__ masks,
                                                  unsigned int* __restrict__ counter) {
    if (blockIdx.x == 0 && threadIdx.x == 0) *counter = 0u;
    const int wv = threadIdx.x >> 6, l = threadIdx.x & 63;
    const int r = blockIdx.x * 4 + wv;             // 0..2047
    const float* trow = target + (size_t)r * W;
    float t0 = trow[l], t1 = trow[l + 64], t2 = trow[l + 128], t3 = trow[l + 192];
    unsigned long long m0 = __ballot(t0 == 0.0f);
    unsigned long long m1 = __ballot(t1 == 0.0f);
    unsigned long long m2 = __ballot(t2 == 0.0f);
    unsigned long long m3 = __ballot(t3 == 0.0f);
    if (l < 4) {
        unsigned long long m = (l == 0) ? m0 : (l == 1) ? m1 : (l == 2) ? m2 : m3;
        masks[(size_t)r * 4 + l] = m;
    }
}

// K2: register-only envelope. Lane l holds g^2 for rows l+64j (j=0..3) of this
// block's 2 columns; the k-loop broadcasts them via v_readlane (k is wave-
// uniform) -> no LDS reads, no lgkm waits, no barrier in the hot loop.
// Last block (threadfence+ticket) folds the 1024 partials into the scalar.
__global__ void __launch_bounds__(256) edt_bce_main(
        const unsigned long long* __restrict__ masks, const float* __restrict__ pred,
        const float* __restrict__ target,
        float* __restrict__ pmx, float* __restrict__ psb, float* __restrict__ psdb,
        unsigned int* __restrict__ counter, float* __restrict__ out) {
    __shared__ float red[3][4];
    __shared__ unsigned int lastFlag;

    const int tid = threadIdx.x;                 // output row i
    const int wv = tid >> 6, l = tid & 63;
    const int b  = blockIdx.x >> 7;              // image
    const int w0 = (blockIdx.x & 127) * CT;      // column tile base

    // ---- global loads up front ----
    const size_t off = ((size_t)(b * H + tid)) * W + w0;
    const float2 p2 = *(const float2*)(pred + off);      // consumed at the end
    const float2 t2 = *(const float2*)(target + off);
    ulonglong2 ma[4], mb[4];
    #pragma unroll
    for (int j = 0; j < 4; ++j) {
        const ulonglong2* mp =
            (const ulonglong2*)(masks + ((size_t)(b * H + (j << 6) + l)) * 4);
        ma[j] = mp[0];
        mb[j] = mp[1];
    }

    // ---- Phase 1: per-lane row-EDT^2 at the 2 columns, rows l+64j ----
    float2 h[4];
    #pragma unroll
    for (int j = 0; j < 4; ++j) {
        unsigned long long mw[4] = {ma[j].x, ma[j].y, mb[j].x, mb[j].y};
        float g[CT];
        #pragma unroll
        for (int c = 0; c < CT; ++c) {
            const int p = w0 + c;
            int best = 1 << 20;
            #pragma unroll
            for (int w = 0; w < 4; ++w) {
                const int rel = p - (w << 6);
                const unsigned long long m = mw[w];
                unsigned long long mlo = (rel < 0)  ? 0ull
                                       : (rel >= 63) ? m : (m & ((2ull << rel) - 1ull));
                unsigned long long mhi = (rel <= 0) ? m
                                       : (rel > 63)  ? 0ull : (m & (~0ull << rel));
                if (mlo) best = min(best, rel - (63 - __builtin_clzll(mlo)));
                if (mhi) best = min(best, __builtin_ctzll(mhi) - rel);
            }
            float d = (best > 255) ? 1e4f : (float)best;   // INF per reference
            g[c] = d * d;
        }
        h[j] = make_float2(g[0], g[1]);
    }

    // ---- Phase 2: envelope over all k via register broadcast (v_readlane) ----
    // fmaf(dA,dA,g2) == round(exact) == reference's g2 + (i-k)^2 (dk2 exact).
    const float fi = (float)tid;
    float acc0 = 3.0e38f, acc1 = 3.0e38f;
    #pragma unroll
    for (int j = 0; j < 4; ++j) {
        float dA = fi - (float)(j << 6);
        const int hx = __float_as_int(h[j].x), hy = __float_as_int(h[j].y);
        #pragma unroll 16
        for (int kk = 0; kk < 64; ++kk) {
            float g0 = __int_as_float(__builtin_amdgcn_readlane(hx, kk));
            float g1 = __int_as_float(__builtin_amdgcn_readlane(hy, kk));
            acc0 = fminf(acc0, fmaf(dA, dA, g0));
            acc1 = fminf(acc1, fmaf(dA, dA, g1));
            dA -= 1.0f;
        }
    }

    // ---- Epilogue: fused BCE + per-block partials ----
    float mx = fmaxf(acc0, acc1);
    float b0 = bce_logits(p2.x, t2.x);
    float b1 = bce_logits(p2.y, t2.y);
    float sb  = b0 + b1;
    float sdb = sqrtf(acc0) * b0 + sqrtf(acc1) * b1;

    #pragma unroll
    for (int o = 32; o > 0; o >>= 1) {
        mx  = fmaxf(mx, __shfl_down(mx, o, 64));
        sb  += __shfl_down(sb, o, 64);
        sdb += __shfl_down(sdb, o, 64);
    }
    if (l == 0) { red[0][wv] = mx; red[1][wv] = sb; red[2][wv] = sdb; }
    __syncthreads();
    if (tid == 0) {
        pmx [blockIdx.x] = fmaxf(fmaxf(red[0][0], red[0][1]), fmaxf(red[0][2], red[0][3]));
        psb [blockIdx.x] = (red[1][0] + red[1][1]) + (red[1][2] + red[1][3]);
        psdb[blockIdx.x] = (red[2][0] + red[2][1]) + (red[2][2] + red[2][3]);
        __threadfence();                                  // partials visible device-wide
        unsigned int t = atomicAdd(counter, 1u);          // device-scope by default
        lastFlag = (t == NBLK - 1) ? 1u : 0u;
    }
    __syncthreads();

    // ---- Last block: combine 1024 partials -> scalar (deterministic) ----
    if (lastFlag) {
        __threadfence();                                  // acquire side
        const int img = tid >> 5, j = tid & 31;           // 8 images x 32 threads
        const int base = (img << 7) + j;
        float fmx = 0.0f, fsb = 0.0f, fsdb = 0.0f;
        #pragma unroll
        for (int q = 0; q < 4; ++q) {
            const int e = base + 32 * q;
            fmx  = fmaxf(fmx, pmx[e]);
            fsb  += psb[e];
            fsdb += psdb[e];
        }
        #pragma unroll
        for (int o = 16; o > 0; o >>= 1) {                // width-32 stays per-image
            fmx  = fmaxf(fmx, __shfl_down(fmx, o, 32));
            fsb  += __shfl_down(fsb, o, 32);
            fsdb += __shfl_down(fsdb, o, 32);
        }
        __shared__ float cimg[8], simg[8];
        if (j == 0) {
            cimg[img] = fsdb / (sqrtf(fmx) + 1e-7f);      // sqrt commutes with max
            simg[img] = fsb;
        }
        __syncthreads();
        if (tid == 0) {
            float tot = 0.0f;
            #pragma unroll
            for (int i = 0; i < 8; ++i) tot += simg[i] + cimg[i];
            out[0] = tot * (1.0f / (float)NPIX);
        }
    }
}

extern "C" void kernel_launch(void* const* d_in, const int* in_sizes, int n_in,
                              void* d_out, int out_size, void* d_ws, size_t ws_size,
                              hipStream_t stream) {
    const float* pred   = (const float*)d_in[0];
    const float* target = (const float*)d_in[1];

    unsigned long long* masks = (unsigned long long*)d_ws;        // 64 KB
    float* pmx  = (float*)((char*)d_ws + (size_t)NROWS * 4 * sizeof(unsigned long long));
    float* psb  = pmx + NBLK;
    float* psdb = psb + NBLK;
    unsigned int* counter = (unsigned int*)(psdb + NBLK);

    make_masks<<<NROWS / 4, 256, 0, stream>>>(target, masks, counter);
    edt_bce_main<<<NBLK, 256, 0, stream>>>(masks, pred, target, pmx, psb, psdb,
                                           counter, (float*)d_out);
}

// Round 9
// 75.566 us; speedup vs baseline: 1.1744x; 1.1744x over previous
//
#include <hip/hip_runtime.h>
#include <math.h>

#define BATCH 8
#define H 256
#define W 256
#define NPIX (BATCH * H * W)
#define NBLK2 512   // K2 blocks: 8 img x 4 colstrips x 16 rowstrips

__device__ __forceinline__ float bce_logits(float p, float t) {
    return fmaxf(p, 0.0f) - p * t + log1pf(expf(-fabsf(p)));
}

// K1: row EDT^2 via ballot masks. Block = (image, row-quad k4): computes
// g2 for rows 4k4..4k4+3 at col tid, stores k-quad-interleaved:
// gi4[(b*64+k4)*256 + w] = float4(g2[4k4+0][w], .., g2[4k4+3][w])
// so K2's k-loop reads one coalesced float4 per 4 k per 64 columns.
__global__ void __launch_bounds__(256) row_edt4(const float* __restrict__ target,
                                                float4* __restrict__ gi4) {
    __shared__ unsigned long long mlds[4][4];
    const int tid = threadIdx.x;
    const int v = tid >> 6, l = tid & 63;
    const float* imgr = target + (size_t)blockIdx.x * 4 * W;   // rows 4k4.. of image b

    #pragma unroll
    for (int j = 0; j < 4; ++j) {
        float t = imgr[j * W + tid];
        unsigned long long m = __ballot(t == 0.0f);
        if (l == 0) mlds[j][v] = m;
    }
    __syncthreads();

    const int p = tid;                     // column
    float g[4];
    #pragma unroll
    for (int j = 0; j < 4; ++j) {
        unsigned long long mw[4] = {mlds[j][0], mlds[j][1], mlds[j][2], mlds[j][3]};
        int best = 1 << 20;
        #pragma unroll
        for (int w = 0; w < 4; ++w) {
            const int rel = p - (w << 6);
            const unsigned long long m = mw[w];
            unsigned long long mlo = (rel < 0)  ? 0ull
                                   : (rel >= 63) ? m : (m & ((2ull << rel) - 1ull));
            unsigned long long mhi = (rel <= 0) ? m
                                   : (rel > 63)  ? 0ull : (m & (~0ull << rel));
            if (mlo) best = min(best, rel - (63 - __builtin_clzll(mlo)));
            if (mhi) best = min(best, __builtin_ctzll(mhi) - rel);
        }
        float d = (best > 255) ? 1e4f : (float)best;    // INF per reference
        g[j] = d * d;
    }
    gi4[(size_t)blockIdx.x * 256 + tid] = make_float4(g[0], g[1], g[2], g[3]);
}

// K2: column envelope + fused BCE. Lane = column (64 cols/block), wave = 4 rows
// (16 rows/block). Inner loop: one coalesced L2-hot float4 load per 4 k —
// lane-varying, zero LDS, zero barriers until the epilogue reduction.
__global__ void __launch_bounds__(256) envelope_bce(
        const float4* __restrict__ gi4, const float* __restrict__ pred,
        const float* __restrict__ target,
        float* __restrict__ pmx, float* __restrict__ psb, float* __restrict__ psdb) {
    __shared__ float red[3][4];
    const int tid = threadIdx.x;
    const int wv = tid >> 6, l = tid & 63;
    const int b  = blockIdx.x >> 6;               // image
    const int cs = (blockIdx.x >> 4) & 3;         // column strip (64 cols)
    const int rs = blockIdx.x & 15;               // row strip (16 rows)
    const int c  = (cs << 6) + l;                 // this lane's column
    const int i0 = (rs << 4) + (wv << 2);         // this lane's 4 rows: i0..i0+3

    const float4* gp = gi4 + (size_t)b * 64 * 256 + c;

    float acc0 = 3.0e38f, acc1 = 3.0e38f, acc2 = 3.0e38f, acc3 = 3.0e38f;
    // d_r = (i0+r) - k, maintained incrementally; fmaf(d,d,g) == reference
    // g2 + (i-k)^2 (dk2 exact integer < 2^24, single rounding both ways).
    float d0 = (float)i0, d1 = d0 + 1.0f, d2 = d0 + 2.0f, d3 = d0 + 3.0f;
    #pragma unroll 4
    for (int k4 = 0; k4 < 64; ++k4) {
        float4 g = gp[(size_t)k4 * 256];          // g2 at k=4k4..4k4+3, col c
        float e0, e1, e2, e3;
        e0 = d0; e1 = d1; e2 = d2; e3 = d3;
        acc0 = fminf(acc0, fminf(fmaf(e0, e0, g.x), fmaf(e0 - 1.0f, e0 - 1.0f, g.y)));
        acc1 = fminf(acc1, fminf(fmaf(e1, e1, g.x), fmaf(e1 - 1.0f, e1 - 1.0f, g.y)));
        acc2 = fminf(acc2, fminf(fmaf(e2, e2, g.x), fmaf(e2 - 1.0f, e2 - 1.0f, g.y)));
        acc3 = fminf(acc3, fminf(fmaf(e3, e3, g.x), fmaf(e3 - 1.0f, e3 - 1.0f, g.y)));
        e0 -= 2.0f; e1 -= 2.0f; e2 -= 2.0f; e3 -= 2.0f;
        acc0 = fminf(acc0, fminf(fmaf(e0, e0, g.z), fmaf(e0 - 1.0f, e0 - 1.0f, g.w)));
        acc1 = fminf(acc1, fminf(fmaf(e1, e1, g.z), fmaf(e1 - 1.0f, e1 - 1.0f, g.w)));
        acc2 = fminf(acc2, fminf(fmaf(e2, e2, g.z), fmaf(e2 - 1.0f, e2 - 1.0f, g.w)));
        acc3 = fminf(acc3, fminf(fmaf(e3, e3, g.z), fmaf(e3 - 1.0f, e3 - 1.0f, g.w)));
        d0 -= 4.0f; d1 -= 4.0f; d2 -= 4.0f; d3 -= 4.0f;
    }

    // ---- Epilogue: BCE at the 4 (row, c) pixels; per-row loads coalesced ----
    const float* pp = pred   + ((size_t)(b * H + i0)) * W + c;
    const float* tp = target + ((size_t)(b * H + i0)) * W + c;
    float p0 = pp[0], p1 = pp[W], p2 = pp[2 * W], p3 = pp[3 * W];
    float t0 = tp[0], t1 = tp[W], t2 = tp[2 * W], t3 = tp[3 * W];

    float mx = fmaxf(fmaxf(acc0, acc1), fmaxf(acc2, acc3));
    float b0 = bce_logits(p0, t0), b1 = bce_logits(p1, t1);
    float b2 = bce_logits(p2, t2), b3 = bce_logits(p3, t3);
    float sb  = (b0 + b1) + (b2 + b3);
    float sdb = (sqrtf(acc0) * b0 + sqrtf(acc1) * b1)
              + (sqrtf(acc2) * b2 + sqrtf(acc3) * b3);

    #pragma unroll
    for (int o = 32; o > 0; o >>= 1) {
        mx  = fmaxf(mx, __shfl_down(mx, o, 64));
        sb  += __shfl_down(sb, o, 64);
        sdb += __shfl_down(sdb, o, 64);
    }
    if (l == 0) { red[0][wv] = mx; red[1][wv] = sb; red[2][wv] = sdb; }
    __syncthreads();
    if (tid == 0) {
        pmx [blockIdx.x] = fmaxf(fmaxf(red[0][0], red[0][1]), fmaxf(red[0][2], red[0][3]));
        psb [blockIdx.x] = (red[1][0] + red[1][1]) + (red[1][2] + red[1][3]);
        psdb[blockIdx.x] = (red[2][0] + red[2][1]) + (red[2][2] + red[2][3]);
    }
}

// K3: 512 partials -> scalar. Images are contiguous 64-block runs.
__global__ void final_reduce(const float* __restrict__ pmx, const float* __restrict__ psb,
                             const float* __restrict__ psdb, float* __restrict__ out) {
    const int tid = threadIdx.x;
    const int img = tid >> 5, j = tid & 31;        // 8 images x 32 threads
    const int e0 = (img << 6) + j, e1 = e0 + 32;
    float mx  = fmaxf(pmx[e0], pmx[e1]);
    float sb  = psb[e0] + psb[e1];
    float sdb = psdb[e0] + psdb[e1];
    #pragma unroll
    for (int o = 16; o > 0; o >>= 1) {             // width-32 groups stay per-image
        mx  = fmaxf(mx, __shfl_down(mx, o, 32));
        sb  += __shfl_down(sb, o, 32);
        sdb += __shfl_down(sdb, o, 32);
    }
    __shared__ float cimg[8], simg[8];
    if (j == 0) {
        cimg[img] = sdb / (sqrtf(mx) + 1e-7f);     // sqrt commutes with max
        simg[img] = sb;
    }
    __syncthreads();
    if (tid == 0) {
        float tot = 0.0f;
        #pragma unroll
        for (int i = 0; i < 8; ++i) tot += simg[i] + cimg[i];
        out[0] = tot * (1.0f / (float)NPIX);
    }
}

extern "C" void kernel_launch(void* const* d_in, const int* in_sizes, int n_in,
                              void* d_out, int out_size, void* d_ws, size_t ws_size,
                              hipStream_t stream) {
    const float* pred   = (const float*)d_in[0];
    const float* target = (const float*)d_in[1];

    float4* gi4 = (float4*)d_ws;                                  // 2 MB
    float* pmx  = (float*)((char*)d_ws + (size_t)BATCH * 64 * 256 * sizeof(float4));
    float* psb  = pmx + NBLK2;
    float* psdb = psb + NBLK2;

    row_edt4<<<BATCH * 64, 256, 0, stream>>>(target, gi4);        // 512 blocks
    envelope_bce<<<NBLK2, 256, 0, stream>>>(gi4, pred, target, pmx, psb, psdb);
    final_reduce<<<1, 256, 0, stream>>>(pmx, psb, psdb, (float*)d_out);
}